// Round 1
// baseline (5020.954 us; speedup 1.0000x reference)
//
#include <hip/hip_runtime.h>
#include <math.h>

#define NB   4
#define NC   64
#define NHh  512
#define NWw  512
#define HWs  (NHh*NWw)
#define ROWB 392          // bytes per token row in LDS (192 bf16 + pad, 8B aligned)
#define EPSLN 1e-5f

__device__ __forceinline__ float lo16(unsigned int u){ union{unsigned int i; float f;} z; z.i=u<<16;          return z.f; }
__device__ __forceinline__ float hi16(unsigned int u){ union{unsigned int i; float f;} z; z.i=u&0xffff0000u;  return z.f; }
__device__ __forceinline__ float b2f (unsigned short v){ union{unsigned int i; float f;} z; z.i=(unsigned int)v<<16; return z.f; }
__device__ __forceinline__ unsigned short f2bf(float f){
  union{float g; unsigned int u;} a; a.g=f;
  unsigned int r = a.u + 0x7fffu + ((a.u>>16)&1u);   // RNE (finite values only)
  return (unsigned short)(r>>16);
}

// ---- setup: fuse out_proj and extra proj into one 64x64 GEMM ----
// W'[c][k] = sum_m proj_w[c][m]*out_w[m][k];  b'[c] = proj_w[c][:]@out_b + proj_b[c]
__global__ void fuse_proj_kernel(const float* __restrict__ out_w, const float* __restrict__ out_b,
                                 const float* __restrict__ proj_w, const float* __restrict__ proj_b,
                                 float* __restrict__ Wf, float* __restrict__ bf){
  int i = blockIdx.x*blockDim.x + threadIdx.x;
  if (i >= 64*64) return;
  int c = i>>6, k = i&63;
  float acc = 0.f;
  for (int m=0;m<64;m++) acc += proj_w[c*64+m]*out_w[m*64+k];
  Wf[i] = acc;
  if (k==0){
    float ab = proj_b[c];
    for (int m=0;m<64;m++) ab += proj_w[c*64+m]*out_b[m];
    bf[c] = ab;
  }
}

// One 64-thread wave per 8x8 window; thread t owns token t = (r*8+s).
// LDS row layout per token (ROWB bytes):
//   phase A: bf16 qkv  -> q bytes [0,128), k [128,256), v [256,384)
//   phase B: bf16 row2 -> bytes [0,128);  bf16 h[128] -> bytes [128,384)
__global__ __launch_bounds__(64,2) void hat_main(
    const float* __restrict__ x,
    const float* __restrict__ n1g, const float* __restrict__ n1b,
    const float* __restrict__ inw, const float* __restrict__ inb,
    const float* __restrict__ Wf,  const float* __restrict__ bfv,
    const float* __restrict__ n2g, const float* __restrict__ n2b,
    const float* __restrict__ w1,  const float* __restrict__ b1,
    const float* __restrict__ w2,  const float* __restrict__ b2,
    float* __restrict__ out)
{
  __shared__ unsigned char smem[64*ROWB];
  const int t  = threadIdx.x;
  const int n  = blockIdx.x;
  const int ww = n & 63;
  const int wh = (n>>6) & 63;
  const int b  = n>>12;
  const int r  = t>>3, s = t&7;
  const size_t pix = (size_t)(wh*8+r)*NWw + (ww*8+s);
  const float* xp = x + (size_t)b*NC*HWs + pix;

  unsigned short* myrow = (unsigned short*)(smem + t*ROWB);

  // ---- load token row + LN1 ----
  float tn[64];
  #pragma unroll
  for (int c=0;c<64;c++) tn[c] = xp[(size_t)c*HWs];
  float mu = 0.f;
  #pragma unroll
  for (int c=0;c<64;c++) mu += tn[c];
  mu *= (1.f/64.f);
  float var = 0.f;
  #pragma unroll
  for (int c=0;c<64;c++){ float d = tn[c]-mu; var += d*d; }
  var *= (1.f/64.f);
  float rstd = rsqrtf(var + EPSLN);
  #pragma unroll
  for (int c=0;c<64;c++) tn[c] = (tn[c]-mu)*rstd*n1g[c] + n1b[c];

  // ---- packed qkv projection -> LDS (bf16) ----
  #pragma unroll 2
  for (int j=0;j<192;j++){
    const float* wr = inw + j*64;
    float a0=inb[j],a1=0.f,a2=0.f,a3=0.f;
    #pragma unroll
    for (int c=0;c<64;c+=4){
      a0+=tn[c  ]*wr[c  ]; a1+=tn[c+1]*wr[c+1];
      a2+=tn[c+2]*wr[c+2]; a3+=tn[c+3]*wr[c+3];
    }
    myrow[j] = f2bf((a0+a1)+(a2+a3));
  }
  __syncthreads();

  // ---- attention (2 heads, dh=32); per-token-serial softmax ----
  float o[64];
  const float scale = 0.17677669529663688f; // 1/sqrt(32)
  #pragma unroll
  for (int h=0;h<2;h++){
    float qh[32];
    {
      const unsigned int* qp = (const unsigned int*)(myrow + h*32);
      #pragma unroll
      for (int i=0;i<16;i++){ unsigned int u = qp[i]; qh[2*i]=lo16(u); qh[2*i+1]=hi16(u); }
    }
    // pass 1: row max
    float m = -3.0e38f;
    #pragma unroll 2
    for (int j=0;j<64;j++){
      const unsigned int* kp = (const unsigned int*)(smem + j*ROWB + 128 + 64*h);
      float a0=0.f,a1=0.f;
      #pragma unroll
      for (int i=0;i<16;i++){ unsigned int u=kp[i]; a0+=qh[2*i]*lo16(u); a1+=qh[2*i+1]*hi16(u); }
      m = fmaxf(m, (a0+a1)*scale);
    }
    // pass 2: exp + sum + PV
    float l = 0.f;
    float oh[32];
    #pragma unroll
    for (int d=0; d<32; d++) oh[d]=0.f;
    #pragma unroll 1
    for (int j=0;j<64;j++){
      const unsigned int* kp = (const unsigned int*)(smem + j*ROWB + 128 + 64*h);
      float a0=0.f,a1=0.f;
      #pragma unroll
      for (int i=0;i<16;i++){ unsigned int u=kp[i]; a0+=qh[2*i]*lo16(u); a1+=qh[2*i+1]*hi16(u); }
      float p = __expf((a0+a1)*scale - m);
      l += p;
      const unsigned int* vp = (const unsigned int*)(smem + j*ROWB + 256 + 64*h);
      #pragma unroll
      for (int i=0;i<16;i++){ unsigned int u=vp[i]; oh[2*i]+=p*lo16(u); oh[2*i+1]+=p*hi16(u); }
    }
    float inv = 1.f/l;
    #pragma unroll
    for (int d=0; d<32; d++) o[h*32+d] = oh[d]*inv;
  }
  __syncthreads();

  // ---- reload x row -> seed row2 (bf16 at bytes [0,128)) ----
  #pragma unroll 2
  for (int c=0;c<64;c++) myrow[c] = f2bf(xp[(size_t)c*HWs]);

  // ---- fused (out_proj ∘ proj) + residual ----
  #pragma unroll 2
  for (int c=0;c<64;c++){
    const float* wr = Wf + c*64;
    float a0=bfv[c],a1=0.f,a2=0.f,a3=0.f;
    #pragma unroll
    for (int k=0;k<64;k+=4){
      a0+=o[k  ]*wr[k  ]; a1+=o[k+1]*wr[k+1];
      a2+=o[k+2]*wr[k+2]; a3+=o[k+3]*wr[k+3];
    }
    myrow[c] = f2bf(b2f(myrow[c]) + (a0+a1)+(a2+a3));
  }

  // ---- LN2 ----
  float r2[64];
  {
    const unsigned int* rp = (const unsigned int*)myrow;
    #pragma unroll
    for (int i=0;i<32;i++){ unsigned int u=rp[i]; r2[2*i]=lo16(u); r2[2*i+1]=hi16(u); }
  }
  float mu2 = 0.f;
  #pragma unroll
  for (int c=0;c<64;c++) mu2 += r2[c];
  mu2 *= (1.f/64.f);
  float v2 = 0.f;
  #pragma unroll
  for (int c=0;c<64;c++){ float d=r2[c]-mu2; v2 += d*d; }
  v2 *= (1.f/64.f);
  float rstd2 = rsqrtf(v2 + EPSLN);
  #pragma unroll
  for (int c=0;c<64;c++) r2[c] = (r2[c]-mu2)*rstd2*n2g[c] + n2b[c];

  // ---- MLP fc1 + exact gelu -> LDS h (bf16 at shorts [64,192)) ----
  #pragma unroll 2
  for (int j=0;j<128;j++){
    const float* wr = w1 + j*64;
    float a0=b1[j],a1=0.f,a2=0.f,a3=0.f;
    #pragma unroll
    for (int c=0;c<64;c+=4){
      a0+=r2[c  ]*wr[c  ]; a1+=r2[c+1]*wr[c+1];
      a2+=r2[c+2]*wr[c+2]; a3+=r2[c+3]*wr[c+3];
    }
    float hv = (a0+a1)+(a2+a3);
    hv = 0.5f*hv*(1.f + erff(hv*0.70710678118654752f));
    myrow[64+j] = f2bf(hv);
  }

  // ---- hoist h to regs, MLP fc2 + residual + store ----
  float hreg[128];
  {
    const unsigned int* hp = (const unsigned int*)(myrow + 64);
    #pragma unroll
    for (int i=0;i<64;i++){ unsigned int u=hp[i]; hreg[2*i]=lo16(u); hreg[2*i+1]=hi16(u); }
  }
  float* op = out + (size_t)b*NC*HWs + pix;
  #pragma unroll 1
  for (int c=0;c<64;c++){
    const float* wr = w2 + c*128;
    float a0=b2[c],a1=0.f,a2=0.f,a3=0.f;
    #pragma unroll
    for (int j=0;j<128;j+=4){
      a0+=hreg[j  ]*wr[j  ]; a1+=hreg[j+1]*wr[j+1];
      a2+=hreg[j+2]*wr[j+2]; a3+=hreg[j+3]*wr[j+3];
    }
    op[(size_t)c*HWs] = b2f(myrow[c]) + (a0+a1)+(a2+a3);
  }
}

extern "C" void kernel_launch(void* const* d_in, const int* in_sizes, int n_in,
                              void* d_out, int out_size, void* d_ws, size_t ws_size,
                              hipStream_t stream) {
  const float* x    = (const float*)d_in[0];
  const float* n1g  = (const float*)d_in[1];
  const float* n1b  = (const float*)d_in[2];
  const float* inw  = (const float*)d_in[3];
  const float* inb  = (const float*)d_in[4];
  const float* outw = (const float*)d_in[5];
  const float* outb = (const float*)d_in[6];
  const float* pw   = (const float*)d_in[7];
  const float* pb   = (const float*)d_in[8];
  const float* n2g  = (const float*)d_in[9];
  const float* n2b  = (const float*)d_in[10];
  const float* w1   = (const float*)d_in[11];
  const float* b1   = (const float*)d_in[12];
  const float* w2   = (const float*)d_in[13];
  const float* b2   = (const float*)d_in[14];

  float* Wf = (float*)d_ws;        // 64*64 fused weight
  float* bf = Wf + 64*64;          // 64 fused bias

  hipLaunchKernelGGL(fuse_proj_kernel, dim3(16), dim3(256), 0, stream,
                     outw, outb, pw, pb, Wf, bf);
  hipLaunchKernelGGL(hat_main, dim3(16384), dim3(64), 0, stream,
                     x, n1g, n1b, inw, inb, Wf, bf, n2g, n2b,
                     w1, b1, w2, b2, (float*)d_out);
}

// Round 2
// 3366.347 us; speedup vs baseline: 1.4915x; 1.4915x over previous
//
#include <hip/hip_runtime.h>
#include <math.h>

#define HWs (512*512)

typedef short  s8v __attribute__((ext_vector_type(8)));   // 8 bf16 (4 VGPRs)
typedef float  f4v __attribute__((ext_vector_type(4)));   // MFMA acc

__device__ __forceinline__ float lo16(unsigned int u){ union{unsigned int i; float f;} z; z.i=u<<16;         return z.f; }
__device__ __forceinline__ float hi16(unsigned int u){ union{unsigned int i; float f;} z; z.i=u&0xffff0000u; return z.f; }
__device__ __forceinline__ unsigned short f2bf(float f){
  union{float g; unsigned int u;} a; a.g=f;
  unsigned int r = a.u + 0x7fffu + ((a.u>>16)&1u);   // RNE (finite)
  return (unsigned short)(r>>16);
}
__device__ __forceinline__ unsigned int pack2(float a, float b){
  return (unsigned int)f2bf(a) | ((unsigned int)f2bf(b)<<16);
}

// XOR swizzle: byte-column perturbation per row; keeps 16B alignment.
#define SWZ(row) (((((row)&7) ^ (((row)>>3)&7)))<<4)

// ---------------- setup kernels ----------------
// ws (u16 units): [0,12288) in_w bf16 | [12288,20480) w1 bf16 | [20480,28672) w2 bf16
//                 [28672,32768) Wf bf16 | byte 65536: bfv (64 f32)
__global__ void conv_wb(const float* __restrict__ inw, const float* __restrict__ w1,
                        const float* __restrict__ w2, unsigned short* __restrict__ ws){
  int i = blockIdx.x*256 + threadIdx.x;
  if (i < 12288)      ws[i] = f2bf(inw[i]);
  else if (i < 20480) ws[i] = f2bf(w1[i-12288]);
  else                ws[i] = f2bf(w2[i-20480]);
}

__global__ void fuse_proj_kernel(const float* __restrict__ out_w, const float* __restrict__ out_b,
                                 const float* __restrict__ proj_w, const float* __restrict__ proj_b,
                                 unsigned short* __restrict__ wf_bf, float* __restrict__ bfv){
  int i = blockIdx.x*256 + threadIdx.x;
  if (i >= 64*64) return;
  int c = i>>6, k = i&63;
  float acc = 0.f;
  for (int m=0;m<64;m++) acc += proj_w[c*64+m]*out_w[m*64+k];
  wf_bf[i] = f2bf(acc);
  if (k==0){
    float ab = proj_b[c];
    for (int m=0;m<64;m++) ab += proj_w[c*64+m]*out_b[m];
    bfv[c] = ab;
  }
}

// ---------------- main kernel: 1 wave = 1 window ----------------
// LDS: 4 regions [64 rows][64 bf16] (128B rows, XOR-swizzled).
// RA: tn -> P -> ln2 -> mlp2out ; RB: q -> o -> h0 ; RC: k -> projout -> h1 ; RD: V^T
__global__ void hat_main(
    const float* __restrict__ x,
    const float* __restrict__ n1g, const float* __restrict__ n1b,
    const float* __restrict__ inb,
    const unsigned short* __restrict__ wbf,
    const float* __restrict__ bfv,
    const float* __restrict__ n2g, const float* __restrict__ n2b,
    const float* __restrict__ b1, const float* __restrict__ b2,
    float* __restrict__ out)
{
  __shared__ __align__(16) unsigned char lds[32768];
  #define RA 0
  #define RB 8192
  #define RC 16384
  #define RD 24576

  const int l = threadIdx.x;
  const int g = l>>4, c = l&15;
  const int n = blockIdx.x;
  const int ww = n&63, wh = (n>>6)&63, b = n>>12;
  const size_t pix = (size_t)(wh*8 + (l>>3))*512 + ww*8 + (l&7);
  const float* xp = x + (size_t)b*64*HWs + pix;

  const unsigned short* inw_bf = wbf;
  const unsigned short* w1_bf  = wbf + 12288;
  const unsigned short* w2_bf  = wbf + 20480;
  const unsigned short* wf_bf  = wbf + 28672;

  // ---------- phase 0: load x row, LN1, stage tn rows -> RA ----------
  float xr[64];
  #pragma unroll
  for (int i=0;i<64;i++) xr[i] = xp[(size_t)i*HWs];
  unsigned int xres[32];
  #pragma unroll
  for (int i=0;i<32;i++) xres[i] = pack2(xr[2*i], xr[2*i+1]);

  float mu = 0.f;
  #pragma unroll
  for (int i=0;i<64;i++) mu += xr[i];
  mu *= (1.f/64.f);
  float var = 0.f;
  #pragma unroll
  for (int i=0;i<64;i++){ float d = xr[i]-mu; var += d*d; }
  var *= (1.f/64.f);
  float rstd = rsqrtf(var + 1e-5f);

  #pragma unroll
  for (int ch=0; ch<8; ch++){
    float t[8];
    #pragma unroll
    for (int i=0;i<8;i++) t[i] = (xr[8*ch+i]-mu)*rstd*n1g[8*ch+i] + n1b[8*ch+i];
    uint4 W;
    W.x = pack2(t[0],t[1]); W.y = pack2(t[2],t[3]);
    W.z = pack2(t[4],t[5]); W.w = pack2(t[6],t[7]);
    *(uint4*)(lds + RA + l*128 + ((16*ch) ^ SWZ(l))) = W;
  }
  __syncthreads();

  // A-fragments of tn (held for all 3 QKV chunks)
  s8v a[4][2];
  #pragma unroll
  for (int tm=0;tm<4;tm++)
    #pragma unroll
    for (int kk=0;kk<2;kk++)
      a[tm][kk] = *(const s8v*)(lds + RA + (16*tm+c)*128 + ((64*kk+16*g) ^ SWZ(16*tm+c)));

  const float scale = 0.17677669529663688f; // 1/sqrt(32)

  // ---------- phase 1: QKV ----------
  // q,k chunks -> straight-write RB/RC
  #pragma unroll 1
  for (int chunk=0; chunk<2; chunk++){
    f4v acc[4][4] = {};
    #pragma unroll
    for (int kk=0;kk<2;kk++)
      #pragma unroll
      for (int tn=0;tn<4;tn++){
        s8v bf = *(const s8v*)(inw_bf + (64*chunk+16*tn+c)*64 + 32*kk + 8*g);
        #pragma unroll
        for (int tm=0;tm<4;tm++)
          acc[tm][tn] = __builtin_amdgcn_mfma_f32_16x16x32_bf16(a[tm][kk], bf, acc[tm][tn], 0,0,0);
      }
    const int reg = RB + 8192*chunk;
    #pragma unroll
    for (int tn=0;tn<4;tn++){
      float bias = inb[64*chunk + 16*tn + c];
      #pragma unroll
      for (int tm=0;tm<4;tm++){
        int row0 = 16*tm + 4*g;
        #pragma unroll
        for (int r=0;r<4;r++){
          float v = acc[tm][tn][r] + bias;
          if (chunk==0) v *= scale;
          *(unsigned short*)(lds + reg + (row0+r)*128 + ((2*(16*tn+c)) ^ SWZ(row0+r))) = f2bf(v);
        }
      }
    }
  }
  // v chunk -> transposed write to RD (V^T[d][tok])
  {
    f4v acc[4][4] = {};
    #pragma unroll
    for (int kk=0;kk<2;kk++)
      #pragma unroll
      for (int tn=0;tn<4;tn++){
        s8v bf = *(const s8v*)(inw_bf + (128+16*tn+c)*64 + 32*kk + 8*g);
        #pragma unroll
        for (int tm=0;tm<4;tm++)
          acc[tm][tn] = __builtin_amdgcn_mfma_f32_16x16x32_bf16(a[tm][kk], bf, acc[tm][tn], 0,0,0);
      }
    #pragma unroll
    for (int tn=0;tn<4;tn++){
      float bias = inb[128 + 16*tn + c];
      int drow = 16*tn + c;
      #pragma unroll
      for (int tm=0;tm<4;tm++)
        #pragma unroll
        for (int r=0;r<4;r++){
          int tok = 16*tm + 4*g + r;
          *(unsigned short*)(lds + RD + drow*128 + ((2*tok) ^ SWZ(drow))) = f2bf(acc[tm][tn][r] + bias);
        }
    }
  }
  __syncthreads();

  // ---------- phase 2: attention ----------
  f4v oacc[4][4] = {};
  #pragma unroll
  for (int h=0; h<2; h++){
    // S = q @ k^T : A = q rows (RB), B^T = k rows (RC)
    f4v sacc[4][4] = {};
    s8v qa[4];
    #pragma unroll
    for (int tm=0;tm<4;tm++)
      qa[tm] = *(const s8v*)(lds + RB + (16*tm+c)*128 + ((64*h+16*g) ^ SWZ(16*tm+c)));
    #pragma unroll
    for (int tn=0;tn<4;tn++){
      s8v kb = *(const s8v*)(lds + RC + (16*tn+c)*128 + ((64*h+16*g) ^ SWZ(16*tn+c)));
      #pragma unroll
      for (int tm=0;tm<4;tm++)
        sacc[tm][tn] = __builtin_amdgcn_mfma_f32_16x16x32_bf16(qa[tm], kb, sacc[tm][tn], 0,0,0);
    }
    // softmax over columns (j): in-lane over tn, shfl over c
    float mrow[4][4], lr[4][4];
    #pragma unroll
    for (int tm=0;tm<4;tm++)
      #pragma unroll
      for (int r=0;r<4;r++)
        mrow[tm][r] = fmaxf(fmaxf(sacc[tm][0][r],sacc[tm][1][r]), fmaxf(sacc[tm][2][r],sacc[tm][3][r]));
    #pragma unroll
    for (int mk=1; mk<16; mk<<=1)
      #pragma unroll
      for (int tm=0;tm<4;tm++)
        #pragma unroll
        for (int r=0;r<4;r++)
          mrow[tm][r] = fmaxf(mrow[tm][r], __shfl_xor(mrow[tm][r], mk));
    #pragma unroll
    for (int tm=0;tm<4;tm++)
      #pragma unroll
      for (int r=0;r<4;r++){
        float s0 = 0.f;
        #pragma unroll
        for (int tn=0;tn<4;tn++){
          float p = __expf(sacc[tm][tn][r] - mrow[tm][r]);
          sacc[tm][tn][r] = p; s0 += p;
        }
        lr[tm][r] = s0;
      }
    #pragma unroll
    for (int mk=1; mk<16; mk<<=1)
      #pragma unroll
      for (int tm=0;tm<4;tm++)
        #pragma unroll
        for (int r=0;r<4;r++)
          lr[tm][r] += __shfl_xor(lr[tm][r], mk);
    // write P (normalized) -> RA
    #pragma unroll
    for (int tm=0;tm<4;tm++)
      #pragma unroll
      for (int r=0;r<4;r++){
        float inv = 1.f/lr[tm][r];
        int row = 16*tm + 4*g + r;
        #pragma unroll
        for (int tn=0;tn<4;tn++)
          *(unsigned short*)(lds + RA + row*128 + ((2*(16*tn+c)) ^ SWZ(row))) = f2bf(sacc[tm][tn][r]*inv);
      }
    __syncthreads();
    // PV : A = P rows (RA), B^T = V^T rows (RD)
    s8v pa[4][2];
    #pragma unroll
    for (int tm=0;tm<4;tm++)
      #pragma unroll
      for (int kk=0;kk<2;kk++)
        pa[tm][kk] = *(const s8v*)(lds + RA + (16*tm+c)*128 + ((64*kk+16*g) ^ SWZ(16*tm+c)));
    #pragma unroll
    for (int kk=0;kk<2;kk++)
      #pragma unroll
      for (int tnl=0;tnl<2;tnl++){
        int vrow = 32*h + 16*tnl + c;
        s8v vb = *(const s8v*)(lds + RD + vrow*128 + ((64*kk+16*g) ^ SWZ(vrow)));
        #pragma unroll
        for (int tm=0;tm<4;tm++)
          oacc[tm][2*h+tnl] = __builtin_amdgcn_mfma_f32_16x16x32_bf16(pa[tm][kk], vb, oacc[tm][2*h+tnl], 0,0,0);
      }
    __syncthreads();
  }
  // write o -> RB (rows [tok][d])
  #pragma unroll
  for (int tm=0;tm<4;tm++)
    #pragma unroll
    for (int r=0;r<4;r++){
      int row = 16*tm + 4*g + r;
      #pragma unroll
      for (int tn=0;tn<4;tn++)
        *(unsigned short*)(lds + RB + row*128 + ((2*(16*tn+c)) ^ SWZ(row))) = f2bf(oacc[tm][tn][r]);
    }
  __syncthreads();

  // ---------- phase 3: fused proj ----------
  {
    s8v oa[4][2];
    #pragma unroll
    for (int tm=0;tm<4;tm++)
      #pragma unroll
      for (int kk=0;kk<2;kk++)
        oa[tm][kk] = *(const s8v*)(lds + RB + (16*tm+c)*128 + ((64*kk+16*g) ^ SWZ(16*tm+c)));
    f4v acc[4][4] = {};
    #pragma unroll
    for (int kk=0;kk<2;kk++)
      #pragma unroll
      for (int tn=0;tn<4;tn++){
        s8v bf = *(const s8v*)(wf_bf + (16*tn+c)*64 + 32*kk + 8*g);
        #pragma unroll
        for (int tm=0;tm<4;tm++)
          acc[tm][tn] = __builtin_amdgcn_mfma_f32_16x16x32_bf16(oa[tm][kk], bf, acc[tm][tn], 0,0,0);
      }
    #pragma unroll
    for (int tn=0;tn<4;tn++){
      float bias = bfv[16*tn+c];
      #pragma unroll
      for (int tm=0;tm<4;tm++)
        #pragma unroll
        for (int r=0;r<4;r++){
          int row = 16*tm + 4*g + r;
          *(unsigned short*)(lds + RC + row*128 + ((2*(16*tn+c)) ^ SWZ(row))) = f2bf(acc[tm][tn][r] + bias);
        }
    }
  }
  __syncthreads();

  // ---------- phase 4: residual + LN2 (lane-per-token) ----------
  {
    float row2[64];
    #pragma unroll
    for (int i=0;i<8;i++){
      uint4 W = *(const uint4*)(lds + RC + l*128 + ((16*i) ^ SWZ(l)));
      row2[8*i+0] = lo16(W.x); row2[8*i+1] = hi16(W.x);
      row2[8*i+2] = lo16(W.y); row2[8*i+3] = hi16(W.y);
      row2[8*i+4] = lo16(W.z); row2[8*i+5] = hi16(W.z);
      row2[8*i+6] = lo16(W.w); row2[8*i+7] = hi16(W.w);
    }
    #pragma unroll
    for (int i=0;i<32;i++){ row2[2*i] += lo16(xres[i]); row2[2*i+1] += hi16(xres[i]); }

    float mu2 = 0.f;
    #pragma unroll
    for (int i=0;i<64;i++) mu2 += row2[i];
    mu2 *= (1.f/64.f);
    float v2 = 0.f;
    #pragma unroll
    for (int i=0;i<64;i++){ float d = row2[i]-mu2; v2 += d*d; }
    v2 *= (1.f/64.f);
    float rstd2 = rsqrtf(v2 + 1e-5f);

    #pragma unroll
    for (int ch=0; ch<8; ch++){
      float t[8];
      #pragma unroll
      for (int i=0;i<8;i++) t[i] = (row2[8*ch+i]-mu2)*rstd2*n2g[8*ch+i] + n2b[8*ch+i];
      uint4 W;
      W.x = pack2(t[0],t[1]); W.y = pack2(t[2],t[3]);
      W.z = pack2(t[4],t[5]); W.w = pack2(t[6],t[7]);
      *(uint4*)(lds + RA + l*128 + ((16*ch) ^ SWZ(l))) = W;
    }
    #pragma unroll
    for (int i=0;i<32;i++) xres[i] = pack2(row2[2*i], row2[2*i+1]);   // keep row2 for final residual
  }
  __syncthreads();

  // ---------- phase 5: MLP1 + gelu ----------
  {
    s8v la[4][2];
    #pragma unroll
    for (int tm=0;tm<4;tm++)
      #pragma unroll
      for (int kk=0;kk<2;kk++)
        la[tm][kk] = *(const s8v*)(lds + RA + (16*tm+c)*128 + ((64*kk+16*g) ^ SWZ(16*tm+c)));
    #pragma unroll 1
    for (int nch=0; nch<2; nch++){
      f4v acc[4][4] = {};
      #pragma unroll
      for (int kk=0;kk<2;kk++)
        #pragma unroll
        for (int tn=0;tn<4;tn++){
          s8v bf = *(const s8v*)(w1_bf + (64*nch+16*tn+c)*64 + 32*kk + 8*g);
          #pragma unroll
          for (int tm=0;tm<4;tm++)
            acc[tm][tn] = __builtin_amdgcn_mfma_f32_16x16x32_bf16(la[tm][kk], bf, acc[tm][tn], 0,0,0);
        }
      const int reg = RB + 8192*nch;
      #pragma unroll
      for (int tn=0;tn<4;tn++){
        float bias = b1[64*nch + 16*tn + c];
        #pragma unroll
        for (int tm=0;tm<4;tm++)
          #pragma unroll
          for (int r=0;r<4;r++){
            float v = acc[tm][tn][r] + bias;
            float z = v*(1.595769122f + 0.071354816f*v*v);     // 2*sqrt(2/pi)*(v + 0.044715 v^3)
            float sg = 1.f/(1.f + __expf(-z));                 // gelu ~ v*sigmoid(z)
            int row = 16*tm + 4*g + r;
            *(unsigned short*)(lds + reg + row*128 + ((2*(16*tn+c)) ^ SWZ(row))) = f2bf(v*sg);
          }
      }
    }
  }
  __syncthreads();

  // ---------- phase 6: MLP2 ----------
  {
    f4v acc[4][4] = {};
    #pragma unroll
    for (int kk=0;kk<4;kk++){
      const int reg = RB + 8192*(kk>>1);
      s8v ha[4];
      #pragma unroll
      for (int tm=0;tm<4;tm++)
        ha[tm] = *(const s8v*)(lds + reg + (16*tm+c)*128 + ((64*(kk&1)+16*g) ^ SWZ(16*tm+c)));
      #pragma unroll
      for (int tn=0;tn<4;tn++){
        s8v bf = *(const s8v*)(w2_bf + (16*tn+c)*128 + 32*kk + 8*g);
        #pragma unroll
        for (int tm=0;tm<4;tm++)
          acc[tm][tn] = __builtin_amdgcn_mfma_f32_16x16x32_bf16(ha[tm], bf, acc[tm][tn], 0,0,0);
      }
    }
    #pragma unroll
    for (int tn=0;tn<4;tn++){
      float bias = b2[16*tn+c];
      #pragma unroll
      for (int tm=0;tm<4;tm++)
        #pragma unroll
        for (int r=0;r<4;r++){
          int row = 16*tm + 4*g + r;
          *(unsigned short*)(lds + RA + row*128 + ((2*(16*tn+c)) ^ SWZ(row))) = f2bf(acc[tm][tn][r] + bias);
        }
    }
  }
  __syncthreads();

  // ---------- epilogue: + residual, store ----------
  float* op = out + (size_t)b*64*HWs + pix;
  #pragma unroll
  for (int i=0;i<8;i++){
    uint4 W = *(const uint4*)(lds + RA + l*128 + ((16*i) ^ SWZ(l)));
    float v0 = lo16(W.x), v1 = hi16(W.x), v2 = lo16(W.y), v3 = hi16(W.y);
    float v4 = lo16(W.z), v5 = hi16(W.z), v6 = lo16(W.w), v7 = hi16(W.w);
    op[(size_t)(8*i+0)*HWs] = v0 + lo16(xres[4*i+0]);
    op[(size_t)(8*i+1)*HWs] = v1 + hi16(xres[4*i+0]);
    op[(size_t)(8*i+2)*HWs] = v2 + lo16(xres[4*i+1]);
    op[(size_t)(8*i+3)*HWs] = v3 + hi16(xres[4*i+1]);
    op[(size_t)(8*i+4)*HWs] = v4 + lo16(xres[4*i+2]);
    op[(size_t)(8*i+5)*HWs] = v5 + hi16(xres[4*i+2]);
    op[(size_t)(8*i+6)*HWs] = v6 + lo16(xres[4*i+3]);
    op[(size_t)(8*i+7)*HWs] = v7 + hi16(xres[4*i+3]);
  }
}

extern "C" void kernel_launch(void* const* d_in, const int* in_sizes, int n_in,
                              void* d_out, int out_size, void* d_ws, size_t ws_size,
                              hipStream_t stream) {
  const float* x    = (const float*)d_in[0];
  const float* n1g  = (const float*)d_in[1];
  const float* n1b  = (const float*)d_in[2];
  const float* inw  = (const float*)d_in[3];
  const float* inb  = (const float*)d_in[4];
  const float* outw = (const float*)d_in[5];
  const float* outb = (const float*)d_in[6];
  const float* pw   = (const float*)d_in[7];
  const float* pb   = (const float*)d_in[8];
  const float* n2g  = (const float*)d_in[9];
  const float* n2b  = (const float*)d_in[10];
  const float* w1   = (const float*)d_in[11];
  const float* b1   = (const float*)d_in[12];
  const float* w2   = (const float*)d_in[13];
  const float* b2   = (const float*)d_in[14];

  unsigned short* wsu = (unsigned short*)d_ws;
  unsigned short* wf_bf = wsu + 28672;
  float* bfv = (float*)((char*)d_ws + 65536);

  hipLaunchKernelGGL(conv_wb, dim3(112), dim3(256), 0, stream, inw, w1, w2, wsu);
  hipLaunchKernelGGL(fuse_proj_kernel, dim3(16), dim3(256), 0, stream, outw, outb, pw, pb, wf_bf, bfv);
  hipLaunchKernelGGL(hat_main, dim3(16384), dim3(64), 0, stream,
                     x, n1g, n1b, inb, wsu, bfv, n2g, n2b, b1, b2, (float*)d_out);
}

// Round 3
// 795.324 us; speedup vs baseline: 6.3131x; 4.2327x over previous
//
#include <hip/hip_runtime.h>
#include <math.h>

#define HWs (512*512)
#define WINSZ 32768

typedef short  s8v __attribute__((ext_vector_type(8)));   // 8 bf16 (4 VGPRs)
typedef float  f4v __attribute__((ext_vector_type(4)));   // MFMA acc

__device__ __forceinline__ float lo16(unsigned int u){ union{unsigned int i; float f;} z; z.i=u<<16;         return z.f; }
__device__ __forceinline__ float hi16(unsigned int u){ union{unsigned int i; float f;} z; z.i=u&0xffff0000u; return z.f; }
__device__ __forceinline__ unsigned short f2bf(float f){
  union{float g; unsigned int u;} a; a.g=f;
  unsigned int r = a.u + 0x7fffu + ((a.u>>16)&1u);   // RNE (finite)
  return (unsigned short)(r>>16);
}
__device__ __forceinline__ unsigned int pack2(float a, float b){
  return (unsigned int)f2bf(a) | ((unsigned int)f2bf(b)<<16);
}

// XOR swizzle: byte-column perturbation per row; keeps 16B alignment.
#define SWZ(row) (((((row)&7) ^ (((row)>>3)&7)))<<4)

// ---------------- setup kernels ----------------
__global__ void conv_wb(const float* __restrict__ inw, const float* __restrict__ w1,
                        const float* __restrict__ w2, unsigned short* __restrict__ ws){
  int i = blockIdx.x*256 + threadIdx.x;
  if (i < 12288)      ws[i] = f2bf(inw[i]);
  else if (i < 20480) ws[i] = f2bf(w1[i-12288]);
  else                ws[i] = f2bf(w2[i-20480]);
}

__global__ void fuse_proj_kernel(const float* __restrict__ out_w, const float* __restrict__ out_b,
                                 const float* __restrict__ proj_w, const float* __restrict__ proj_b,
                                 unsigned short* __restrict__ wf_bf, float* __restrict__ bfv){
  int i = blockIdx.x*256 + threadIdx.x;
  if (i >= 64*64) return;
  int c = i>>6, k = i&63;
  float acc = 0.f;
  for (int m=0;m<64;m++) acc += proj_w[c*64+m]*out_w[m*64+k];
  wf_bf[i] = f2bf(acc);
  if (k==0){
    float ab = proj_b[c];
    for (int m=0;m<64;m++) ab += proj_w[c*64+m]*out_b[m];
    bfv[c] = ab;
  }
}

// ---------------- main kernel: 256 threads = 4 waves = 4 adjacent windows ----------------
// Per-window LDS (32KB): RA tn->P->ln2->mlp2out ; RB q->h0 ; RC k->projout->h1 ; RD V^T
// Thread phases (load/LN1/LN2/store): thread t <-> (win=(t>>3)&3, tok=(t>>5)*8+(t&7))
// Wave phases (MFMA): wave w <-> window w
__global__ __launch_bounds__(256,1) void hat_main(
    const float* __restrict__ x,
    const float* __restrict__ n1g, const float* __restrict__ n1b,
    const float* __restrict__ inb,
    const unsigned short* __restrict__ wbf,
    const float* __restrict__ bfv,
    const float* __restrict__ n2g, const float* __restrict__ n2b,
    const float* __restrict__ b1, const float* __restrict__ b2,
    float* __restrict__ out)
{
  __shared__ __align__(16) unsigned char lds[131072];
  #define RA 0
  #define RB 8192
  #define RC 16384
  #define RD 24576

  const int t  = threadIdx.x;
  const int l  = t & 63;
  const int g  = l>>4, c = l&15;
  const int w  = t>>6;                  // compute wave -> window index
  const int wb = w<<15;                 // wave's window LDS base
  const int win  = (t>>3)&3;            // thread's window (load/store map)
  const int winb = win<<15;
  const int tok  = ((t>>5)<<3) | (t&7); // thread's token

  const int n = blockIdx.x;
  const int ww4 = n & 15, wh = (n>>4)&63, b = n>>10;
  const size_t pix = (size_t)(wh*8 + (t>>5))*512 + ww4*32 + (t&31);
  const float* xp = x + (size_t)b*64*HWs + pix;

  const unsigned short* inw_bf = wbf;
  const unsigned short* w1_bf  = wbf + 12288;
  const unsigned short* w2_bf  = wbf + 20480;
  const unsigned short* wf_bf  = wbf + 28672;

  // ---------- phase 0 (thread map): coalesced load, LN1, stage tn ----------
  float xr[64];
  #pragma unroll
  for (int i=0;i<64;i++) xr[i] = xp[(size_t)i*HWs];
  unsigned int xres[32];
  #pragma unroll
  for (int i=0;i<32;i++) xres[i] = pack2(xr[2*i], xr[2*i+1]);

  float mu = 0.f;
  #pragma unroll
  for (int i=0;i<64;i++) mu += xr[i];
  mu *= (1.f/64.f);
  float var = 0.f;
  #pragma unroll
  for (int i=0;i<64;i++){ float d = xr[i]-mu; var += d*d; }
  var *= (1.f/64.f);
  float rstd = rsqrtf(var + 1e-5f);

  #pragma unroll
  for (int ch=0; ch<8; ch++){
    float tv[8];
    #pragma unroll
    for (int i=0;i<8;i++) tv[i] = (xr[8*ch+i]-mu)*rstd*n1g[8*ch+i] + n1b[8*ch+i];
    uint4 W;
    W.x = pack2(tv[0],tv[1]); W.y = pack2(tv[2],tv[3]);
    W.z = pack2(tv[4],tv[5]); W.w = pack2(tv[6],tv[7]);
    *(uint4*)(lds + winb + RA + tok*128 + ((16*ch) ^ SWZ(tok))) = W;
  }
  __syncthreads();

  // ---------- wave map from here: A-fragments of tn ----------
  s8v a[4][2];
  #pragma unroll
  for (int tm=0;tm<4;tm++)
    #pragma unroll
    for (int kk=0;kk<2;kk++)
      a[tm][kk] = *(const s8v*)(lds + wb + RA + (16*tm+c)*128 + ((64*kk+16*g) ^ SWZ(16*tm+c)));

  const float scale = 0.17677669529663688f; // 1/sqrt(32)

  // ---------- phase 1: QKV ----------
  #pragma unroll 1
  for (int chunk=0; chunk<2; chunk++){
    f4v acc[4][4] = {};
    #pragma unroll
    for (int kk=0;kk<2;kk++)
      #pragma unroll
      for (int tn=0;tn<4;tn++){
        s8v bf = *(const s8v*)(inw_bf + (64*chunk+16*tn+c)*64 + 32*kk + 8*g);
        #pragma unroll
        for (int tm=0;tm<4;tm++)
          acc[tm][tn] = __builtin_amdgcn_mfma_f32_16x16x32_bf16(a[tm][kk], bf, acc[tm][tn], 0,0,0);
      }
    const int reg = RB + 8192*chunk;
    #pragma unroll
    for (int tn=0;tn<4;tn++){
      float bias = inb[64*chunk + 16*tn + c];
      #pragma unroll
      for (int tm=0;tm<4;tm++){
        int row0 = 16*tm + 4*g;
        #pragma unroll
        for (int r=0;r<4;r++){
          float v = acc[tm][tn][r] + bias;
          if (chunk==0) v *= scale;
          *(unsigned short*)(lds + wb + reg + (row0+r)*128 + ((2*(16*tn+c)) ^ SWZ(row0+r))) = f2bf(v);
        }
      }
    }
  }
  {
    f4v acc[4][4] = {};
    #pragma unroll
    for (int kk=0;kk<2;kk++)
      #pragma unroll
      for (int tn=0;tn<4;tn++){
        s8v bf = *(const s8v*)(inw_bf + (128+16*tn+c)*64 + 32*kk + 8*g);
        #pragma unroll
        for (int tm=0;tm<4;tm++)
          acc[tm][tn] = __builtin_amdgcn_mfma_f32_16x16x32_bf16(a[tm][kk], bf, acc[tm][tn], 0,0,0);
      }
    #pragma unroll
    for (int tn=0;tn<4;tn++){
      float bias = inb[128 + 16*tn + c];
      int drow = 16*tn + c;
      #pragma unroll
      for (int tm=0;tm<4;tm++)
        #pragma unroll
        for (int r=0;r<4;r++){
          int tk = 16*tm + 4*g + r;
          *(unsigned short*)(lds + wb + RD + drow*128 + ((2*tk) ^ SWZ(drow))) = f2bf(acc[tm][tn][r] + bias);
        }
    }
  }
  __syncthreads();

  // ---------- phase 2: attention ----------
  f4v oacc[4][4] = {};
  #pragma unroll
  for (int h=0; h<2; h++){
    f4v sacc[4][4] = {};
    s8v qa[4];
    #pragma unroll
    for (int tm=0;tm<4;tm++)
      qa[tm] = *(const s8v*)(lds + wb + RB + (16*tm+c)*128 + ((64*h+16*g) ^ SWZ(16*tm+c)));
    #pragma unroll
    for (int tn=0;tn<4;tn++){
      s8v kb = *(const s8v*)(lds + wb + RC + (16*tn+c)*128 + ((64*h+16*g) ^ SWZ(16*tn+c)));
      #pragma unroll
      for (int tm=0;tm<4;tm++)
        sacc[tm][tn] = __builtin_amdgcn_mfma_f32_16x16x32_bf16(qa[tm], kb, sacc[tm][tn], 0,0,0);
    }
    float mrow[4][4], lr[4][4];
    #pragma unroll
    for (int tm=0;tm<4;tm++)
      #pragma unroll
      for (int r=0;r<4;r++)
        mrow[tm][r] = fmaxf(fmaxf(sacc[tm][0][r],sacc[tm][1][r]), fmaxf(sacc[tm][2][r],sacc[tm][3][r]));
    #pragma unroll
    for (int mk=1; mk<16; mk<<=1)
      #pragma unroll
      for (int tm=0;tm<4;tm++)
        #pragma unroll
        for (int r=0;r<4;r++)
          mrow[tm][r] = fmaxf(mrow[tm][r], __shfl_xor(mrow[tm][r], mk));
    #pragma unroll
    for (int tm=0;tm<4;tm++)
      #pragma unroll
      for (int r=0;r<4;r++){
        float s0 = 0.f;
        #pragma unroll
        for (int tn=0;tn<4;tn++){
          float p = __expf(sacc[tm][tn][r] - mrow[tm][r]);
          sacc[tm][tn][r] = p; s0 += p;
        }
        lr[tm][r] = s0;
      }
    #pragma unroll
    for (int mk=1; mk<16; mk<<=1)
      #pragma unroll
      for (int tm=0;tm<4;tm++)
        #pragma unroll
        for (int r=0;r<4;r++)
          lr[tm][r] += __shfl_xor(lr[tm][r], mk);
    #pragma unroll
    for (int tm=0;tm<4;tm++)
      #pragma unroll
      for (int r=0;r<4;r++){
        float inv = 1.f/lr[tm][r];
        int row = 16*tm + 4*g + r;
        #pragma unroll
        for (int tn=0;tn<4;tn++)
          *(unsigned short*)(lds + wb + RA + row*128 + ((2*(16*tn+c)) ^ SWZ(row))) = f2bf(sacc[tm][tn][r]*inv);
      }
    __syncthreads();
    s8v pa[4][2];
    #pragma unroll
    for (int tm=0;tm<4;tm++)
      #pragma unroll
      for (int kk=0;kk<2;kk++)
        pa[tm][kk] = *(const s8v*)(lds + wb + RA + (16*tm+c)*128 + ((64*kk+16*g) ^ SWZ(16*tm+c)));
    #pragma unroll
    for (int kk=0;kk<2;kk++)
      #pragma unroll
      for (int tnl=0;tnl<2;tnl++){
        int vrow = 32*h + 16*tnl + c;
        s8v vb = *(const s8v*)(lds + wb + RD + vrow*128 + ((64*kk+16*g) ^ SWZ(vrow)));
        #pragma unroll
        for (int tm=0;tm<4;tm++)
          oacc[tm][2*h+tnl] = __builtin_amdgcn_mfma_f32_16x16x32_bf16(pa[tm][kk], vb, oacc[tm][2*h+tnl], 0,0,0);
      }
    __syncthreads();
  }
  #pragma unroll
  for (int tm=0;tm<4;tm++)
    #pragma unroll
    for (int r=0;r<4;r++){
      int row = 16*tm + 4*g + r;
      #pragma unroll
      for (int tn=0;tn<4;tn++)
        *(unsigned short*)(lds + wb + RB + row*128 + ((2*(16*tn+c)) ^ SWZ(row))) = f2bf(oacc[tm][tn][r]);
    }
  __syncthreads();

  // ---------- phase 3: fused proj ----------
  {
    s8v oa[4][2];
    #pragma unroll
    for (int tm=0;tm<4;tm++)
      #pragma unroll
      for (int kk=0;kk<2;kk++)
        oa[tm][kk] = *(const s8v*)(lds + wb + RB + (16*tm+c)*128 + ((64*kk+16*g) ^ SWZ(16*tm+c)));
    f4v acc[4][4] = {};
    #pragma unroll
    for (int kk=0;kk<2;kk++)
      #pragma unroll
      for (int tn=0;tn<4;tn++){
        s8v bf = *(const s8v*)(wf_bf + (16*tn+c)*64 + 32*kk + 8*g);
        #pragma unroll
        for (int tm=0;tm<4;tm++)
          acc[tm][tn] = __builtin_amdgcn_mfma_f32_16x16x32_bf16(oa[tm][kk], bf, acc[tm][tn], 0,0,0);
      }
    #pragma unroll
    for (int tn=0;tn<4;tn++){
      float bias = bfv[16*tn+c];
      #pragma unroll
      for (int tm=0;tm<4;tm++)
        #pragma unroll
        for (int r=0;r<4;r++){
          int row = 16*tm + 4*g + r;
          *(unsigned short*)(lds + wb + RC + row*128 + ((2*(16*tn+c)) ^ SWZ(row))) = f2bf(acc[tm][tn][r] + bias);
        }
    }
  }
  __syncthreads();

  // ---------- phase 4 (thread map): residual + LN2 ----------
  {
    float row2[64];
    #pragma unroll
    for (int i=0;i<8;i++){
      uint4 W = *(const uint4*)(lds + winb + RC + tok*128 + ((16*i) ^ SWZ(tok)));
      row2[8*i+0] = lo16(W.x); row2[8*i+1] = hi16(W.x);
      row2[8*i+2] = lo16(W.y); row2[8*i+3] = hi16(W.y);
      row2[8*i+4] = lo16(W.z); row2[8*i+5] = hi16(W.z);
      row2[8*i+6] = lo16(W.w); row2[8*i+7] = hi16(W.w);
    }
    #pragma unroll
    for (int i=0;i<32;i++){ row2[2*i] += lo16(xres[i]); row2[2*i+1] += hi16(xres[i]); }

    float mu2 = 0.f;
    #pragma unroll
    for (int i=0;i<64;i++) mu2 += row2[i];
    mu2 *= (1.f/64.f);
    float v2 = 0.f;
    #pragma unroll
    for (int i=0;i<64;i++){ float d = row2[i]-mu2; v2 += d*d; }
    v2 *= (1.f/64.f);
    float rstd2 = rsqrtf(v2 + 1e-5f);

    #pragma unroll
    for (int ch=0; ch<8; ch++){
      float tv[8];
      #pragma unroll
      for (int i=0;i<8;i++) tv[i] = (row2[8*ch+i]-mu2)*rstd2*n2g[8*ch+i] + n2b[8*ch+i];
      uint4 W;
      W.x = pack2(tv[0],tv[1]); W.y = pack2(tv[2],tv[3]);
      W.z = pack2(tv[4],tv[5]); W.w = pack2(tv[6],tv[7]);
      *(uint4*)(lds + winb + RA + tok*128 + ((16*ch) ^ SWZ(tok))) = W;
    }
    #pragma unroll
    for (int i=0;i<32;i++) xres[i] = pack2(row2[2*i], row2[2*i+1]);
  }
  __syncthreads();

  // ---------- phase 5: MLP1 + gelu ----------
  {
    s8v la[4][2];
    #pragma unroll
    for (int tm=0;tm<4;tm++)
      #pragma unroll
      for (int kk=0;kk<2;kk++)
        la[tm][kk] = *(const s8v*)(lds + wb + RA + (16*tm+c)*128 + ((64*kk+16*g) ^ SWZ(16*tm+c)));
    #pragma unroll 1
    for (int nch=0; nch<2; nch++){
      f4v acc[4][4] = {};
      #pragma unroll
      for (int kk=0;kk<2;kk++)
        #pragma unroll
        for (int tn=0;tn<4;tn++){
          s8v bf = *(const s8v*)(w1_bf + (64*nch+16*tn+c)*64 + 32*kk + 8*g);
          #pragma unroll
          for (int tm=0;tm<4;tm++)
            acc[tm][tn] = __builtin_amdgcn_mfma_f32_16x16x32_bf16(la[tm][kk], bf, acc[tm][tn], 0,0,0);
        }
      const int reg = RB + 8192*nch;
      #pragma unroll
      for (int tn=0;tn<4;tn++){
        float bias = b1[64*nch + 16*tn + c];
        #pragma unroll
        for (int tm=0;tm<4;tm++)
          #pragma unroll
          for (int r=0;r<4;r++){
            float v = acc[tm][tn][r] + bias;
            float z = v*(1.595769122f + 0.071354816f*v*v);
            float sg = 1.f/(1.f + __expf(-z));
            int row = 16*tm + 4*g + r;
            *(unsigned short*)(lds + wb + reg + row*128 + ((2*(16*tn+c)) ^ SWZ(row))) = f2bf(v*sg);
          }
      }
    }
  }
  __syncthreads();

  // ---------- phase 6: MLP2 ----------
  {
    f4v acc[4][4] = {};
    #pragma unroll
    for (int kk=0;kk<4;kk++){
      const int reg = RB + 8192*(kk>>1);
      s8v ha[4];
      #pragma unroll
      for (int tm=0;tm<4;tm++)
        ha[tm] = *(const s8v*)(lds + wb + reg + (16*tm+c)*128 + ((64*(kk&1)+16*g) ^ SWZ(16*tm+c)));
      #pragma unroll
      for (int tn=0;tn<4;tn++){
        s8v bf = *(const s8v*)(w2_bf + (16*tn+c)*128 + 32*kk + 8*g);
        #pragma unroll
        for (int tm=0;tm<4;tm++)
          acc[tm][tn] = __builtin_amdgcn_mfma_f32_16x16x32_bf16(ha[tm], bf, acc[tm][tn], 0,0,0);
      }
    }
    #pragma unroll
    for (int tn=0;tn<4;tn++){
      float bias = b2[16*tn+c];
      #pragma unroll
      for (int tm=0;tm<4;tm++)
        #pragma unroll
        for (int r=0;r<4;r++){
          int row = 16*tm + 4*g + r;
          *(unsigned short*)(lds + wb + RA + row*128 + ((2*(16*tn+c)) ^ SWZ(row))) = f2bf(acc[tm][tn][r] + bias);
        }
    }
  }
  __syncthreads();

  // ---------- epilogue (thread map): + residual, coalesced store ----------
  float* op = out + (size_t)b*64*HWs + pix;
  #pragma unroll
  for (int i=0;i<8;i++){
    uint4 W = *(const uint4*)(lds + winb + RA + tok*128 + ((16*i) ^ SWZ(tok)));
    float v0 = lo16(W.x), v1 = hi16(W.x), v2 = lo16(W.y), v3 = hi16(W.y);
    float v4 = lo16(W.z), v5 = hi16(W.z), v6 = lo16(W.w), v7 = hi16(W.w);
    op[(size_t)(8*i+0)*HWs] = v0 + lo16(xres[4*i+0]);
    op[(size_t)(8*i+1)*HWs] = v1 + hi16(xres[4*i+0]);
    op[(size_t)(8*i+2)*HWs] = v2 + lo16(xres[4*i+1]);
    op[(size_t)(8*i+3)*HWs] = v3 + hi16(xres[4*i+1]);
    op[(size_t)(8*i+4)*HWs] = v4 + lo16(xres[4*i+2]);
    op[(size_t)(8*i+5)*HWs] = v5 + hi16(xres[4*i+2]);
    op[(size_t)(8*i+6)*HWs] = v6 + lo16(xres[4*i+3]);
    op[(size_t)(8*i+7)*HWs] = v7 + hi16(xres[4*i+3]);
  }
}

extern "C" void kernel_launch(void* const* d_in, const int* in_sizes, int n_in,
                              void* d_out, int out_size, void* d_ws, size_t ws_size,
                              hipStream_t stream) {
  const float* x    = (const float*)d_in[0];
  const float* n1g  = (const float*)d_in[1];
  const float* n1b  = (const float*)d_in[2];
  const float* inw  = (const float*)d_in[3];
  const float* inb  = (const float*)d_in[4];
  const float* outw = (const float*)d_in[5];
  const float* outb = (const float*)d_in[6];
  const float* pw   = (const float*)d_in[7];
  const float* pb   = (const float*)d_in[8];
  const float* n2g  = (const float*)d_in[9];
  const float* n2b  = (const float*)d_in[10];
  const float* w1   = (const float*)d_in[11];
  const float* b1   = (const float*)d_in[12];
  const float* w2   = (const float*)d_in[13];
  const float* b2   = (const float*)d_in[14];

  unsigned short* wsu = (unsigned short*)d_ws;
  unsigned short* wf_bf = wsu + 28672;
  float* bfv = (float*)((char*)d_ws + 65536);

  hipLaunchKernelGGL(conv_wb, dim3(112), dim3(256), 0, stream, inw, w1, w2, wsu);
  hipLaunchKernelGGL(fuse_proj_kernel, dim3(16), dim3(256), 0, stream, outw, outb, pw, pb, wf_bf, bfv);
  hipLaunchKernelGGL(hat_main, dim3(4096), dim3(256), 0, stream,
                     x, n1g, n1b, inb, wsu, bfv, n2g, n2b, b1, b2, (float*)d_out);
}

// Round 4
// 769.274 us; speedup vs baseline: 6.5269x; 1.0339x over previous
//
#include <hip/hip_runtime.h>
#include <math.h>

#define HWs (512*512)

typedef short  s8v __attribute__((ext_vector_type(8)));   // 8 bf16 (4 VGPRs)
typedef float  f4v __attribute__((ext_vector_type(4)));   // MFMA acc

__device__ __forceinline__ float lo16(unsigned int u){ union{unsigned int i; float f;} z; z.i=u<<16;         return z.f; }
__device__ __forceinline__ float hi16(unsigned int u){ union{unsigned int i; float f;} z; z.i=u&0xffff0000u; return z.f; }
__device__ __forceinline__ unsigned int cvtpk(float lo, float hi){
  unsigned int r; asm("v_cvt_pk_bf16_f32 %0, %1, %2" : "=v"(r) : "v"(lo), "v"(hi)); return r;
}
__device__ __forceinline__ unsigned short f2bf(float f){ return (unsigned short)cvtpk(f,f); }
__device__ __forceinline__ unsigned short f2bf_rne(float f){
  union{float g; unsigned int u;} a; a.g=f;
  unsigned int r = a.u + 0x7fffu + ((a.u>>16)&1u);
  return (unsigned short)(r>>16);
}

// XOR swizzle on 16B units within a 128B row
#define SWZ(row) (((((row)&7) ^ (((row)>>3)&7)))<<4)

// ---------------- setup kernels ----------------
__global__ void conv_wb(const float* __restrict__ inw, const float* __restrict__ w1,
                        const float* __restrict__ w2, unsigned short* __restrict__ ws){
  int i = blockIdx.x*256 + threadIdx.x;
  if (i < 12288)      ws[i] = f2bf_rne(inw[i]);
  else if (i < 20480) ws[i] = f2bf_rne(w1[i-12288]);
  else                ws[i] = f2bf_rne(w2[i-20480]);
}

__global__ void fuse_proj_kernel(const float* __restrict__ out_w, const float* __restrict__ out_b,
                                 const float* __restrict__ proj_w, const float* __restrict__ proj_b,
                                 unsigned short* __restrict__ wf_bf, float* __restrict__ bfv){
  int i = blockIdx.x*256 + threadIdx.x;
  if (i >= 64*64) return;
  int c = i>>6, k = i&63;
  float acc = 0.f;
  for (int m=0;m<64;m++) acc += proj_w[c*64+m]*out_w[m*64+k];
  wf_bf[i] = f2bf_rne(acc);
  if (k==0){
    float ab = proj_b[c];
    for (int m=0;m<64;m++) ab += proj_w[c*64+m]*out_b[m];
    bfv[c] = ab;
  }
}

// ---------------- main: 1024 threads = 16 waves; 4 windows; 4 waves per window ----------------
// Per-window 32KB: RA tn->P->tn2->mlp2out ; RB q->o->h[0:64] ; RC k->projout ; RD V^T->h[64:128]
// Thread map (ld/LN/st): cb=t>>8 (16ch), pr=(t>>5)&7, pc=t&31; win=(pc>>3)&3, tok=pr*8+(pc&7)
// Wave map (MFMA): wave w: window=w&3, tm=w>>2 (token rows 16tm..16tm+15)
__global__ __launch_bounds__(1024,4) void hat_main(
    const float* __restrict__ x,
    const float* __restrict__ n1g, const float* __restrict__ n1b,
    const float* __restrict__ inb,
    const unsigned short* __restrict__ wbf,
    const float* __restrict__ bfv,
    const float* __restrict__ n2g, const float* __restrict__ n2b,
    const float* __restrict__ b1, const float* __restrict__ b2,
    float* __restrict__ out)
{
  __shared__ __align__(16) unsigned char lds[131072];
  #define RA 0
  #define RB 8192
  #define RC 16384
  #define RD 24576

  const int t = threadIdx.x;
  const int l = t & 63;
  const int g = (l>>4)&3, c = l&15;
  const int w = t>>6;
  const int tm = w>>2;
  const int wb = (w&3)<<15;
  const int cb = t>>8;
  const int pr = (t>>5)&7;
  const int pc = t&31;
  const int tok = pr*8 + (pc&7);
  const int wtb = ((pc>>3)&3)<<15;

  const int n = blockIdx.x;
  const int ww4 = n&15, wh=(n>>4)&63, b=n>>10;
  const size_t pix = (size_t)(wh*8+pr)*512 + ww4*32 + pc;
  const float* xp = x + ((size_t)b*64 + 16*cb)*HWs + pix;

  const unsigned short* inw_bf = wbf;
  const unsigned short* w1_bf  = wbf + 12288;
  const unsigned short* w2_bf  = wbf + 20480;
  const unsigned short* wf_bf  = wbf + 28672;

  // ---------- phase 0a: coalesced load of 16 channels, LN1 partials ----------
  float xr[16];
  #pragma unroll
  for (int i=0;i<16;i++) xr[i] = xp[(size_t)i*HWs];
  {
    float s1=0.f, s2=0.f;
    #pragma unroll
    for (int i=0;i<16;i++){ s1 += xr[i]; s2 += xr[i]*xr[i]; }
    *(float2*)(lds + wtb + RD + tok*32 + cb*8) = make_float2(s1, s2);
  }
  __syncthreads();   // b1

  // ---------- phase 0b: LN1 normalize, stage tn ----------
  unsigned int xres[8];
  {
    float S=0.f, SS=0.f;
    #pragma unroll
    for (int grp=0; grp<4; grp++){
      float2 p = *(const float2*)(lds + wtb + RD + tok*32 + grp*8);
      S += p.x; SS += p.y;
    }
    float mu = S*(1.f/64.f);
    float var = SS*(1.f/64.f) - mu*mu;
    float rstd = rsqrtf(var + 1e-5f);
    float tv[16];
    #pragma unroll
    for (int i=0;i<16;i++) tv[i] = (xr[i]-mu)*rstd*n1g[16*cb+i] + n1b[16*cb+i];
    #pragma unroll
    for (int j=0;j<8;j++) xres[j] = cvtpk(xr[2*j], xr[2*j+1]);
    uint4 W0, W1;
    W0.x=cvtpk(tv[0],tv[1]);  W0.y=cvtpk(tv[2],tv[3]);  W0.z=cvtpk(tv[4],tv[5]);  W0.w=cvtpk(tv[6],tv[7]);
    W1.x=cvtpk(tv[8],tv[9]);  W1.y=cvtpk(tv[10],tv[11]);W1.z=cvtpk(tv[12],tv[13]);W1.w=cvtpk(tv[14],tv[15]);
    int sw = SWZ(tok);
    *(uint4*)(lds + wtb + RA + tok*128 + ((32*cb   ) ^ sw)) = W0;
    *(uint4*)(lds + wtb + RA + tok*128 + ((32*cb+16) ^ sw)) = W1;
  }
  __syncthreads();   // b2

  const int row_a = 16*tm + c;
  const int swa = SWZ(row_a);
  const float scale = 0.17677669529663688f; // 1/sqrt(32)

  // ---------- phase 1: QKV (wave map, tm slice) ----------
  {
    s8v a0 = *(const s8v*)(lds + wb + RA + row_a*128 + ((16*g   ) ^ swa));
    s8v a1 = *(const s8v*)(lds + wb + RA + row_a*128 + ((64+16*g) ^ swa));
    #pragma unroll 1
    for (int chunk=0; chunk<2; chunk++){
      f4v acc[4] = {};
      #pragma unroll
      for (int tn=0;tn<4;tn++){
        s8v bf0 = *(const s8v*)(inw_bf + (64*chunk+16*tn+c)*64 + 8*g);
        s8v bf1 = *(const s8v*)(inw_bf + (64*chunk+16*tn+c)*64 + 32 + 8*g);
        acc[tn] = __builtin_amdgcn_mfma_f32_16x16x32_bf16(a0, bf0, acc[tn], 0,0,0);
        acc[tn] = __builtin_amdgcn_mfma_f32_16x16x32_bf16(a1, bf1, acc[tn], 0,0,0);
      }
      const int reg = (chunk==0) ? RB : RC;
      #pragma unroll
      for (int tn=0;tn<4;tn++){
        float bias = inb[64*chunk + 16*tn + c];
        #pragma unroll
        for (int r=0;r<4;r++){
          float v = acc[tn][r] + bias;
          if (chunk==0) v *= scale;
          int row = 16*tm + 4*g + r;
          *(unsigned short*)(lds + wb + reg + row*128 + ((2*(16*tn+c)) ^ SWZ(row))) = f2bf(v);
        }
      }
    }
    { // V chunk -> transposed packed write to RD
      f4v acc[4] = {};
      #pragma unroll
      for (int tn=0;tn<4;tn++){
        s8v bf0 = *(const s8v*)(inw_bf + (128+16*tn+c)*64 + 8*g);
        s8v bf1 = *(const s8v*)(inw_bf + (128+16*tn+c)*64 + 32 + 8*g);
        acc[tn] = __builtin_amdgcn_mfma_f32_16x16x32_bf16(a0, bf0, acc[tn], 0,0,0);
        acc[tn] = __builtin_amdgcn_mfma_f32_16x16x32_bf16(a1, bf1, acc[tn], 0,0,0);
      }
      #pragma unroll
      for (int tn=0;tn<4;tn++){
        int drow = 16*tn + c;
        float bias = inb[128 + drow];
        uint2 U;
        U.x = cvtpk(acc[tn][0]+bias, acc[tn][1]+bias);
        U.y = cvtpk(acc[tn][2]+bias, acc[tn][3]+bias);
        *(uint2*)(lds + wb + RD + drow*128 + ((2*(16*tm+4*g)) ^ SWZ(drow))) = U;
      }
    }
  }
  __syncthreads();   // b3 (k rows + V^T cross-wave)

  // ---------- phase 2: attention (wave-private rows) ----------
  f4v oacc[4] = {};
  #pragma unroll 1
  for (int h=0; h<2; h++){
    s8v qa = *(const s8v*)(lds + wb + RB + row_a*128 + ((64*h+16*g) ^ swa));
    f4v sacc[4] = {};
    #pragma unroll
    for (int tn=0;tn<4;tn++){
      int kr = 16*tn + c;
      s8v kb = *(const s8v*)(lds + wb + RC + kr*128 + ((64*h+16*g) ^ SWZ(kr)));
      sacc[tn] = __builtin_amdgcn_mfma_f32_16x16x32_bf16(qa, kb, sacc[tn], 0,0,0);
    }
    float mrow[4], lr[4];
    #pragma unroll
    for (int r=0;r<4;r++)
      mrow[r] = fmaxf(fmaxf(sacc[0][r],sacc[1][r]), fmaxf(sacc[2][r],sacc[3][r]));
    #pragma unroll
    for (int mk=1; mk<16; mk<<=1)
      #pragma unroll
      for (int r=0;r<4;r++) mrow[r] = fmaxf(mrow[r], __shfl_xor(mrow[r], mk));
    #pragma unroll
    for (int r=0;r<4;r++){
      float s0 = 0.f;
      #pragma unroll
      for (int tn=0;tn<4;tn++){
        float p = __expf(sacc[tn][r] - mrow[r]);
        sacc[tn][r] = p; s0 += p;
      }
      lr[r] = s0;
    }
    #pragma unroll
    for (int mk=1; mk<16; mk<<=1)
      #pragma unroll
      for (int r=0;r<4;r++) lr[r] += __shfl_xor(lr[r], mk);
    #pragma unroll
    for (int r=0;r<4;r++){
      float inv = 1.f/lr[r];
      int row = 16*tm + 4*g + r;
      int sw = SWZ(row);
      #pragma unroll
      for (int tn=0;tn<4;tn++)
        *(unsigned short*)(lds + wb + RA + row*128 + ((2*(16*tn+c)) ^ sw)) = f2bf(sacc[tn][r]*inv);
    }
    s8v pa0 = *(const s8v*)(lds + wb + RA + row_a*128 + ((16*g   ) ^ swa));
    s8v pa1 = *(const s8v*)(lds + wb + RA + row_a*128 + ((64+16*g) ^ swa));
    #pragma unroll
    for (int tnl=0; tnl<2; tnl++){
      int vr = 32*h + 16*tnl + c;
      int svr = SWZ(vr);
      s8v vb0 = *(const s8v*)(lds + wb + RD + vr*128 + ((16*g   ) ^ svr));
      s8v vb1 = *(const s8v*)(lds + wb + RD + vr*128 + ((64+16*g) ^ svr));
      oacc[2*h+tnl] = __builtin_amdgcn_mfma_f32_16x16x32_bf16(pa0, vb0, oacc[2*h+tnl], 0,0,0);
      oacc[2*h+tnl] = __builtin_amdgcn_mfma_f32_16x16x32_bf16(pa1, vb1, oacc[2*h+tnl], 0,0,0);
    }
  }
  // o -> RB (own rows; q self-reads done)
  #pragma unroll
  for (int r=0;r<4;r++){
    int row = 16*tm + 4*g + r;
    int sw = SWZ(row);
    #pragma unroll
    for (int j=0;j<4;j++)
      *(unsigned short*)(lds + wb + RB + row*128 + ((2*(16*j+c)) ^ sw)) = f2bf(oacc[j][r]);
  }
  __syncthreads();   // b4 (all kb/vb reads done before RC/RD rewritten)

  // ---------- phase 3: fused proj -> RC ----------
  {
    s8v oa0 = *(const s8v*)(lds + wb + RB + row_a*128 + ((16*g   ) ^ swa));
    s8v oa1 = *(const s8v*)(lds + wb + RB + row_a*128 + ((64+16*g) ^ swa));
    f4v acc[4] = {};
    #pragma unroll
    for (int tn=0;tn<4;tn++){
      s8v bf0 = *(const s8v*)(wf_bf + (16*tn+c)*64 + 8*g);
      s8v bf1 = *(const s8v*)(wf_bf + (16*tn+c)*64 + 32 + 8*g);
      acc[tn] = __builtin_amdgcn_mfma_f32_16x16x32_bf16(oa0, bf0, acc[tn], 0,0,0);
      acc[tn] = __builtin_amdgcn_mfma_f32_16x16x32_bf16(oa1, bf1, acc[tn], 0,0,0);
    }
    #pragma unroll
    for (int tn=0;tn<4;tn++){
      float bias = bfv[16*tn+c];
      #pragma unroll
      for (int r=0;r<4;r++){
        int row = 16*tm + 4*g + r;
        *(unsigned short*)(lds + wb + RC + row*128 + ((2*(16*tn+c)) ^ SWZ(row))) = f2bf(acc[tn][r] + bias);
      }
    }
  }
  __syncthreads();   // b5 (-> thread map)

  // ---------- phase 4: residual + LN2 (thread map) ----------
  float row2[16];
  {
    int sw = SWZ(tok);
    uint4 A0 = *(const uint4*)(lds + wtb + RC + tok*128 + ((32*cb   ) ^ sw));
    uint4 A1 = *(const uint4*)(lds + wtb + RC + tok*128 + ((32*cb+16) ^ sw));
    unsigned int pr8[8] = {A0.x,A0.y,A0.z,A0.w,A1.x,A1.y,A1.z,A1.w};
    #pragma unroll
    for (int j=0;j<8;j++){
      row2[2*j]   = lo16(pr8[j]) + lo16(xres[j]);
      row2[2*j+1] = hi16(pr8[j]) + hi16(xres[j]);
    }
    float s1=0.f, s2=0.f;
    #pragma unroll
    for (int i=0;i<16;i++){ s1 += row2[i]; s2 += row2[i]*row2[i]; }
    *(float2*)(lds + wtb + RB + tok*32 + cb*8) = make_float2(s1, s2);
  }
  __syncthreads();   // b6
  {
    float S=0.f, SS=0.f;
    #pragma unroll
    for (int grp=0; grp<4; grp++){
      float2 p = *(const float2*)(lds + wtb + RB + tok*32 + grp*8);
      S += p.x; SS += p.y;
    }
    float mu2 = S*(1.f/64.f);
    float v2 = SS*(1.f/64.f) - mu2*mu2;
    float rstd2 = rsqrtf(v2 + 1e-5f);
    float tv[16];
    #pragma unroll
    for (int i=0;i<16;i++) tv[i] = (row2[i]-mu2)*rstd2*n2g[16*cb+i] + n2b[16*cb+i];
    uint4 W0, W1;
    W0.x=cvtpk(tv[0],tv[1]);  W0.y=cvtpk(tv[2],tv[3]);  W0.z=cvtpk(tv[4],tv[5]);  W0.w=cvtpk(tv[6],tv[7]);
    W1.x=cvtpk(tv[8],tv[9]);  W1.y=cvtpk(tv[10],tv[11]);W1.z=cvtpk(tv[12],tv[13]);W1.w=cvtpk(tv[14],tv[15]);
    int sw = SWZ(tok);
    *(uint4*)(lds + wtb + RA + tok*128 + ((32*cb   ) ^ sw)) = W0;
    *(uint4*)(lds + wtb + RA + tok*128 + ((32*cb+16) ^ sw)) = W1;
  }
  __syncthreads();   // b7 (-> wave map)

  // ---------- phase 5: MLP1 + gelu -> RB (h0), RD (h1) ----------
  {
    s8v la0 = *(const s8v*)(lds + wb + RA + row_a*128 + ((16*g   ) ^ swa));
    s8v la1 = *(const s8v*)(lds + wb + RA + row_a*128 + ((64+16*g) ^ swa));
    #pragma unroll 1
    for (int nch=0; nch<2; nch++){
      f4v acc[4] = {};
      #pragma unroll
      for (int tn=0;tn<4;tn++){
        s8v bf0 = *(const s8v*)(w1_bf + (64*nch+16*tn+c)*64 + 8*g);
        s8v bf1 = *(const s8v*)(w1_bf + (64*nch+16*tn+c)*64 + 32 + 8*g);
        acc[tn] = __builtin_amdgcn_mfma_f32_16x16x32_bf16(la0, bf0, acc[tn], 0,0,0);
        acc[tn] = __builtin_amdgcn_mfma_f32_16x16x32_bf16(la1, bf1, acc[tn], 0,0,0);
      }
      const int reg = nch ? RD : RB;
      #pragma unroll
      for (int tn=0;tn<4;tn++){
        float bias = b1[64*nch + 16*tn + c];
        #pragma unroll
        for (int r=0;r<4;r++){
          float v = acc[tn][r] + bias;
          float z = v*(1.595769122f + 0.071354816f*v*v);
          float sg = 1.f/(1.f + __expf(-z));
          int row = 16*tm + 4*g + r;
          *(unsigned short*)(lds + wb + reg + row*128 + ((2*(16*tn+c)) ^ SWZ(row))) = f2bf(v*sg);
        }
      }
    }
  }
  // ---------- phase 6: MLP2 -> RA (wave-private rows; no barrier needed) ----------
  {
    f4v acc[4] = {};
    #pragma unroll
    for (int kk=0;kk<4;kk++){
      const int reg = (kk<2) ? RB : RD;
      s8v ha = *(const s8v*)(lds + wb + reg + row_a*128 + ((64*(kk&1)+16*g) ^ swa));
      #pragma unroll
      for (int tn=0;tn<4;tn++){
        s8v bf = *(const s8v*)(w2_bf + (16*tn+c)*128 + 32*kk + 8*g);
        acc[tn] = __builtin_amdgcn_mfma_f32_16x16x32_bf16(ha, bf, acc[tn], 0,0,0);
      }
    }
    #pragma unroll
    for (int tn=0;tn<4;tn++){
      float bias = b2[16*tn+c];
      #pragma unroll
      for (int r=0;r<4;r++){
        int row = 16*tm + 4*g + r;
        *(unsigned short*)(lds + wb + RA + row*128 + ((2*(16*tn+c)) ^ SWZ(row))) = f2bf(acc[tn][r] + bias);
      }
    }
  }
  __syncthreads();   // b8 (-> thread map)

  // ---------- epilogue: + residual (row2 regs), coalesced store ----------
  {
    int sw = SWZ(tok);
    uint4 A0 = *(const uint4*)(lds + wtb + RA + tok*128 + ((32*cb   ) ^ sw));
    uint4 A1 = *(const uint4*)(lds + wtb + RA + tok*128 + ((32*cb+16) ^ sw));
    unsigned int pr8[8] = {A0.x,A0.y,A0.z,A0.w,A1.x,A1.y,A1.z,A1.w};
    float* op = out + ((size_t)b*64 + 16*cb)*HWs + pix;
    #pragma unroll
    for (int j=0;j<8;j++){
      op[(size_t)(2*j  )*HWs] = lo16(pr8[j]) + row2[2*j];
      op[(size_t)(2*j+1)*HWs] = hi16(pr8[j]) + row2[2*j+1];
    }
  }
}

extern "C" void kernel_launch(void* const* d_in, const int* in_sizes, int n_in,
                              void* d_out, int out_size, void* d_ws, size_t ws_size,
                              hipStream_t stream) {
  const float* x    = (const float*)d_in[0];
  const float* n1g  = (const float*)d_in[1];
  const float* n1b  = (const float*)d_in[2];
  const float* inw  = (const float*)d_in[3];
  const float* inb  = (const float*)d_in[4];
  const float* outw = (const float*)d_in[5];
  const float* outb = (const float*)d_in[6];
  const float* pw   = (const float*)d_in[7];
  const float* pb   = (const float*)d_in[8];
  const float* n2g  = (const float*)d_in[9];
  const float* n2b  = (const float*)d_in[10];
  const float* w1   = (const float*)d_in[11];
  const float* b1   = (const float*)d_in[12];
  const float* w2   = (const float*)d_in[13];
  const float* b2   = (const float*)d_in[14];

  unsigned short* wsu = (unsigned short*)d_ws;
  unsigned short* wf_bf = wsu + 28672;
  float* bfv = (float*)((char*)d_ws + 65536);

  hipLaunchKernelGGL(conv_wb, dim3(112), dim3(256), 0, stream, inw, w1, w2, wsu);
  hipLaunchKernelGGL(fuse_proj_kernel, dim3(16), dim3(256), 0, stream, outw, outb, pw, pb, wf_bf, bfv);
  hipLaunchKernelGGL(hat_main, dim3(4096), dim3(1024), 0, stream,
                     x, n1g, n1b, inb, wsu, bfv, n2g, n2b, b1, b2, (float*)d_out);
}

// Round 6
// 648.835 us; speedup vs baseline: 7.7384x; 1.1856x over previous
//
#include <hip/hip_runtime.h>
#include <math.h>

#define HWs (512*512)

typedef short  s8v __attribute__((ext_vector_type(8)));   // 8 bf16 (4 VGPRs)
typedef short  s4v __attribute__((ext_vector_type(4)));   // 4 bf16 (2 VGPRs)
typedef float  f4v __attribute__((ext_vector_type(4)));   // MFMA acc

__device__ __forceinline__ float lo16(unsigned int u){ union{unsigned int i; float f;} z; z.i=u<<16;         return z.f; }
__device__ __forceinline__ float hi16(unsigned int u){ union{unsigned int i; float f;} z; z.i=u&0xffff0000u; return z.f; }
__device__ __forceinline__ unsigned int cvtpk(float lo, float hi){
  unsigned int r; asm("v_cvt_pk_bf16_f32 %0, %1, %2" : "=v"(r) : "v"(lo), "v"(hi)); return r;
}
__device__ __forceinline__ unsigned short f2bf_rne(float f){
  union{float g; unsigned int u;} a; a.g=f;
  unsigned int r = a.u + 0x7fffu + ((a.u>>16)&1u);
  return (unsigned short)(r>>16);
}
// short-family LDS stores (TBAA-compatible with s8v loads)
__device__ __forceinline__ void st8(void* p, unsigned int a, unsigned int b){
  union{ unsigned int u[2]; s4v v; } z; z.u[0]=a; z.u[1]=b;
  *(s4v*)p = z.v;
}
__device__ __forceinline__ void st16(void* p, unsigned int a, unsigned int b, unsigned int c, unsigned int d){
  union{ unsigned int u[4]; s8v v; } z; z.u[0]=a; z.u[1]=b; z.u[2]=c; z.u[3]=d;
  *(s8v*)p = z.v;
}

// XOR swizzle on 16B units within a 128B row
#define SWZ(row) (((((row)&7) ^ (((row)>>3)&7)))<<4)

// ---------------- setup kernels ----------------
__global__ void conv_wb(const float* __restrict__ inw, const float* __restrict__ w1,
                        const float* __restrict__ w2, unsigned short* __restrict__ ws){
  int i = blockIdx.x*256 + threadIdx.x;
  if (i < 12288)      ws[i] = f2bf_rne(inw[i]);
  else if (i < 20480) ws[i] = f2bf_rne(w1[i-12288]);
  else                ws[i] = f2bf_rne(w2[i-20480]);
}

__global__ void fuse_proj_kernel(const float* __restrict__ out_w, const float* __restrict__ out_b,
                                 const float* __restrict__ proj_w, const float* __restrict__ proj_b,
                                 unsigned short* __restrict__ wf_bf, float* __restrict__ bfv){
  int i = blockIdx.x*256 + threadIdx.x;
  if (i >= 64*64) return;
  int c = i>>6, k = i&63;
  float acc = 0.f;
  for (int m=0;m<64;m++) acc += proj_w[c*64+m]*out_w[m*64+k];
  wf_bf[i] = f2bf_rne(acc);
  if (k==0){
    float ab = proj_b[c];
    for (int m=0;m<64;m++) ab += proj_w[c*64+m]*out_b[m];
    bfv[c] = ab;
  }
}

// ---------------- main: 512 threads = 8 waves; 2 windows; 4 waves per window ----------------
// Per-window 32KB: RA tn->P->tn2->mlp2out ; RB q->o->h[0:64] ; RC k->projout ; RD V^T->h[64:128]
// Thread map: pc=t&15, pr=(t>>4)&7, cb=t>>7 ; win=(pc>>3)&1, tok=pr*8+(pc&7)
// Wave map: wave w: window=w&1, tm=w>>1 (token rows 16tm..16tm+15)
// GEMM rule: mfma(X, Y): lane (g,c) reg r = dot(Xrow[4g+r], Yrow[c]); frags load elems 8g..8g+7 (+32*kk)
__global__ __launch_bounds__(512,4) void hat_main(
    const float* __restrict__ x,
    const float* __restrict__ n1g, const float* __restrict__ n1b,
    const float* __restrict__ inb,
    const unsigned short* __restrict__ wbf,
    const float* __restrict__ bfv,
    const float* __restrict__ n2g, const float* __restrict__ n2b,
    const float* __restrict__ b1, const float* __restrict__ b2,
    float* __restrict__ out)
{
  __shared__ __align__(16) unsigned char lds[65536];
  #define RA 0
  #define RB 8192
  #define RC 16384
  #define RD 24576

  const int t = threadIdx.x;
  const int l = t & 63;
  const int g = (l>>4)&3, c = l&15;
  const int w  = t>>6;                  // 0..7
  const int tm = w>>1;
  const int wb = (w&1)<<15;
  const int cb = t>>7;                  // 0..3 (16 channels each)
  const int pr = (t>>4)&7;
  const int pc = t&15;
  const int tok = pr*8 + (pc&7);
  const int wtb = ((pc>>3)&1)<<15;

  const int n = blockIdx.x;
  const int ww2 = n&31, wh=(n>>5)&63, b=n>>11;
  const size_t pix = (size_t)(wh*8+pr)*512 + ww2*16 + pc;
  const float* xp = x + ((size_t)b*64 + 16*cb)*HWs + pix;

  const unsigned short* inw_bf = wbf;
  const unsigned short* w1_bf  = wbf + 12288;
  const unsigned short* w2_bf  = wbf + 20480;
  const unsigned short* wf_bf  = wbf + 28672;

  // ---------- phase 0a: coalesced load of 16 channels, LN1 partials ----------
  float xr[16];
  #pragma unroll
  for (int i=0;i<16;i++) xr[i] = xp[(size_t)i*HWs];
  {
    float s1=0.f, s2=0.f;
    #pragma unroll
    for (int i=0;i<16;i++){ s1 += xr[i]; s2 += xr[i]*xr[i]; }
    *(float2*)(lds + wtb + RD + tok*32 + cb*8) = make_float2(s1, s2);
  }
  __syncthreads();   // b1

  // ---------- phase 0b: LN1 normalize, stage tn ----------
  unsigned int xres[8];
  {
    float S=0.f, SS=0.f;
    #pragma unroll
    for (int grp=0; grp<4; grp++){
      float2 p = *(const float2*)(lds + wtb + RD + tok*32 + grp*8);
      S += p.x; SS += p.y;
    }
    float mu = S*(1.f/64.f);
    float var = SS*(1.f/64.f) - mu*mu;
    float rstd = rsqrtf(var + 1e-5f);
    float tv[16];
    #pragma unroll
    for (int i=0;i<16;i++) tv[i] = (xr[i]-mu)*rstd*n1g[16*cb+i] + n1b[16*cb+i];
    #pragma unroll
    for (int j=0;j<8;j++) xres[j] = cvtpk(xr[2*j], xr[2*j+1]);
    int sw = SWZ(tok);
    st16(lds + wtb + RA + tok*128 + ((32*cb   ) ^ sw),
         cvtpk(tv[0],tv[1]), cvtpk(tv[2],tv[3]), cvtpk(tv[4],tv[5]), cvtpk(tv[6],tv[7]));
    st16(lds + wtb + RA + tok*128 + ((32*cb+16) ^ sw),
         cvtpk(tv[8],tv[9]), cvtpk(tv[10],tv[11]), cvtpk(tv[12],tv[13]), cvtpk(tv[14],tv[15]));
  }
  __syncthreads();   // b2

  const int row_a = 16*tm + c;
  const int swa = SWZ(row_a);
  const float scale = 0.17677669529663688f; // 1/sqrt(32)

  // ---------- phase 1: QKV ----------
  s8v a0 = *(const s8v*)(lds + wb + RA + row_a*128 + ((16*g   ) ^ swa));
  s8v a1 = *(const s8v*)(lds + wb + RA + row_a*128 + ((64+16*g) ^ swa));
  #pragma unroll 1
  for (int chunk=0; chunk<2; chunk++){
    f4v acc[4] = {};
    #pragma unroll
    for (int tn=0;tn<4;tn++){
      s8v wf0 = *(const s8v*)(inw_bf + (64*chunk+16*tn+c)*64 + 8*g);
      s8v wf1 = *(const s8v*)(inw_bf + (64*chunk+16*tn+c)*64 + 32 + 8*g);
      acc[tn] = __builtin_amdgcn_mfma_f32_16x16x32_bf16(wf0, a0, acc[tn], 0,0,0);
      acc[tn] = __builtin_amdgcn_mfma_f32_16x16x32_bf16(wf1, a1, acc[tn], 0,0,0);
    }
    const int reg = (chunk==0) ? RB : RC;
    #pragma unroll
    for (int tn=0;tn<4;tn++){
      float4 b4 = *(const float4*)(inb + 64*chunk + 16*tn + 4*g);
      float v0=acc[tn][0]+b4.x, v1=acc[tn][1]+b4.y, v2=acc[tn][2]+b4.z, v3=acc[tn][3]+b4.w;
      if (chunk==0){ v0*=scale; v1*=scale; v2*=scale; v3*=scale; }
      st8(lds + wb + reg + row_a*128 + ((2*(16*tn+4*g)) ^ swa), cvtpk(v0,v1), cvtpk(v2,v3));
    }
  }
  { // V chunk (unflipped) -> transposed packed write to RD (V^T[d][tok])
    f4v acc[4] = {};
    #pragma unroll
    for (int tn=0;tn<4;tn++){
      s8v wf0 = *(const s8v*)(inw_bf + (128+16*tn+c)*64 + 8*g);
      s8v wf1 = *(const s8v*)(inw_bf + (128+16*tn+c)*64 + 32 + 8*g);
      acc[tn] = __builtin_amdgcn_mfma_f32_16x16x32_bf16(a0, wf0, acc[tn], 0,0,0);
      acc[tn] = __builtin_amdgcn_mfma_f32_16x16x32_bf16(a1, wf1, acc[tn], 0,0,0);
    }
    #pragma unroll
    for (int tn=0;tn<4;tn++){
      int drow = 16*tn + c;
      float bias = inb[128 + drow];
      st8(lds + wb + RD + drow*128 + ((2*(16*tm+4*g)) ^ SWZ(drow)),
          cvtpk(acc[tn][0]+bias, acc[tn][1]+bias), cvtpk(acc[tn][2]+bias, acc[tn][3]+bias));
    }
  }
  __syncthreads();   // b3

  // ---------- phase 2: attention ----------
  #pragma unroll 1
  for (int h=0; h<2; h++){
    s8v qa = *(const s8v*)(lds + wb + RB + row_a*128 + ((64*h+16*g) ^ swa));
    f4v sacc[4] = {};
    #pragma unroll
    for (int tn=0;tn<4;tn++){
      int kr = 16*tn + c;
      s8v kb = *(const s8v*)(lds + wb + RC + kr*128 + ((64*h+16*g) ^ SWZ(kr)));
      sacc[tn] = __builtin_amdgcn_mfma_f32_16x16x32_bf16(kb, qa, sacc[tn], 0,0,0);
    }
    // lane (g,c): sacc[tn][r] = S[ktok=16tn+4g+r][qtok=16tm+c]
    float mt[4];
    #pragma unroll
    for (int tn=0;tn<4;tn++)
      mt[tn] = fmaxf(fmaxf(sacc[tn][0],sacc[tn][1]), fmaxf(sacc[tn][2],sacc[tn][3]));
    float m = fmaxf(fmaxf(mt[0],mt[1]), fmaxf(mt[2],mt[3]));
    m = fmaxf(m, __shfl_xor(m, 16));
    m = fmaxf(m, __shfl_xor(m, 32));
    float lsum = 0.f;
    float p[4][4];
    #pragma unroll
    for (int tn=0;tn<4;tn++)
      #pragma unroll
      for (int r=0;r<4;r++){ float e = __expf(sacc[tn][r]-m); p[tn][r]=e; lsum+=e; }
    lsum += __shfl_xor(lsum, 16);
    lsum += __shfl_xor(lsum, 32);
    float inv = 1.f/lsum;
    // P[qtok][ktok] packed write (own row)
    #pragma unroll
    for (int tn=0;tn<4;tn++)
      st8(lds + wb + RA + row_a*128 + ((2*(16*tn+4*g)) ^ swa),
          cvtpk(p[tn][0]*inv, p[tn][1]*inv), cvtpk(p[tn][2]*inv, p[tn][3]*inv));
    asm volatile("" ::: "memory");   // order P writes before pa reads (same-wave RAW)
    // PV: A = V^T rows, B = P rows -> O[qtok][d] packed to RB
    s8v pa0 = *(const s8v*)(lds + wb + RA + row_a*128 + ((16*g   ) ^ swa));
    s8v pa1 = *(const s8v*)(lds + wb + RA + row_a*128 + ((64+16*g) ^ swa));
    #pragma unroll
    for (int tnl=0; tnl<2; tnl++){
      int vr = 32*h + 16*tnl + c;
      int svr = SWZ(vr);
      s8v vb0 = *(const s8v*)(lds + wb + RD + vr*128 + ((16*g   ) ^ svr));
      s8v vb1 = *(const s8v*)(lds + wb + RD + vr*128 + ((64+16*g) ^ svr));
      f4v oc = {};
      oc = __builtin_amdgcn_mfma_f32_16x16x32_bf16(vb0, pa0, oc, 0,0,0);
      oc = __builtin_amdgcn_mfma_f32_16x16x32_bf16(vb1, pa1, oc, 0,0,0);
      st8(lds + wb + RB + row_a*128 + ((64*h + 32*tnl + 8*g) ^ swa),
          cvtpk(oc[0], oc[1]), cvtpk(oc[2], oc[3]));
    }
  }
  __syncthreads();   // b4 (all RC/RD reads done before proj overwrites RC)

  // ---------- phase 3: fused proj -> RC ----------
  {
    s8v oa0 = *(const s8v*)(lds + wb + RB + row_a*128 + ((16*g   ) ^ swa));
    s8v oa1 = *(const s8v*)(lds + wb + RB + row_a*128 + ((64+16*g) ^ swa));
    f4v acc[4] = {};
    #pragma unroll
    for (int tn=0;tn<4;tn++){
      s8v wf0 = *(const s8v*)(wf_bf + (16*tn+c)*64 + 8*g);
      s8v wf1 = *(const s8v*)(wf_bf + (16*tn+c)*64 + 32 + 8*g);
      acc[tn] = __builtin_amdgcn_mfma_f32_16x16x32_bf16(wf0, oa0, acc[tn], 0,0,0);
      acc[tn] = __builtin_amdgcn_mfma_f32_16x16x32_bf16(wf1, oa1, acc[tn], 0,0,0);
    }
    #pragma unroll
    for (int tn=0;tn<4;tn++){
      float4 b4 = *(const float4*)(bfv + 16*tn + 4*g);
      st8(lds + wb + RC + row_a*128 + ((2*(16*tn+4*g)) ^ swa),
          cvtpk(acc[tn][0]+b4.x, acc[tn][1]+b4.y), cvtpk(acc[tn][2]+b4.z, acc[tn][3]+b4.w));
    }
  }
  __syncthreads();   // b5 (-> thread map)

  // ---------- phase 4: residual + LN2 (thread map) ----------
  float row2[16];
  {
    int sw = SWZ(tok);
    uint4 A0 = *(const uint4*)(lds + wtb + RC + tok*128 + ((32*cb   ) ^ sw));
    uint4 A1 = *(const uint4*)(lds + wtb + RC + tok*128 + ((32*cb+16) ^ sw));
    unsigned int pr8[8] = {A0.x,A0.y,A0.z,A0.w,A1.x,A1.y,A1.z,A1.w};
    #pragma unroll
    for (int j=0;j<8;j++){
      row2[2*j]   = lo16(pr8[j]) + lo16(xres[j]);
      row2[2*j+1] = hi16(pr8[j]) + hi16(xres[j]);
    }
    float s1=0.f, s2=0.f;
    #pragma unroll
    for (int i=0;i<16;i++){ s1 += row2[i]; s2 += row2[i]*row2[i]; }
    *(float2*)(lds + wtb + RB + tok*32 + cb*8) = make_float2(s1, s2);
  }
  __syncthreads();   // b6
  {
    float S=0.f, SS=0.f;
    #pragma unroll
    for (int grp=0; grp<4; grp++){
      float2 p = *(const float2*)(lds + wtb + RB + tok*32 + grp*8);
      S += p.x; SS += p.y;
    }
    float mu2 = S*(1.f/64.f);
    float v2 = SS*(1.f/64.f) - mu2*mu2;
    float rstd2 = rsqrtf(v2 + 1e-5f);
    float tv[16];
    #pragma unroll
    for (int i=0;i<16;i++) tv[i] = (row2[i]-mu2)*rstd2*n2g[16*cb+i] + n2b[16*cb+i];
    int sw = SWZ(tok);
    st16(lds + wtb + RA + tok*128 + ((32*cb   ) ^ sw),
         cvtpk(tv[0],tv[1]), cvtpk(tv[2],tv[3]), cvtpk(tv[4],tv[5]), cvtpk(tv[6],tv[7]));
    st16(lds + wtb + RA + tok*128 + ((32*cb+16) ^ sw),
         cvtpk(tv[8],tv[9]), cvtpk(tv[10],tv[11]), cvtpk(tv[12],tv[13]), cvtpk(tv[14],tv[15]));
  }
  __syncthreads();   // b7 (-> wave map)

  // ---------- phase 5: MLP1 + gelu -> RB (h0), RD (h1) ----------
  {
    s8v la0 = *(const s8v*)(lds + wb + RA + row_a*128 + ((16*g   ) ^ swa));
    s8v la1 = *(const s8v*)(lds + wb + RA + row_a*128 + ((64+16*g) ^ swa));
    #pragma unroll 1
    for (int nch=0; nch<2; nch++){
      f4v acc[4] = {};
      #pragma unroll
      for (int tn=0;tn<4;tn++){
        s8v wf0 = *(const s8v*)(w1_bf + (64*nch+16*tn+c)*64 + 8*g);
        s8v wf1 = *(const s8v*)(w1_bf + (64*nch+16*tn+c)*64 + 32 + 8*g);
        acc[tn] = __builtin_amdgcn_mfma_f32_16x16x32_bf16(wf0, la0, acc[tn], 0,0,0);
        acc[tn] = __builtin_amdgcn_mfma_f32_16x16x32_bf16(wf1, la1, acc[tn], 0,0,0);
      }
      const int reg = nch ? RD : RB;
      #pragma unroll
      for (int tn=0;tn<4;tn++){
        float4 b4 = *(const float4*)(b1 + 64*nch + 16*tn + 4*g);
        float vv[4] = {acc[tn][0]+b4.x, acc[tn][1]+b4.y, acc[tn][2]+b4.z, acc[tn][3]+b4.w};
        #pragma unroll
        for (int r=0;r<4;r++){
          float v = vv[r];
          float z = v*(1.595769122f + 0.071354816f*v*v);
          vv[r] = v/(1.f + __expf(-z));
        }
        st8(lds + wb + reg + row_a*128 + ((2*(16*tn+4*g)) ^ swa), cvtpk(vv[0],vv[1]), cvtpk(vv[2],vv[3]));
      }
    }
  }
  asm volatile("" ::: "memory");   // order MLP1 h-writes before MLP2 ha reads (same-wave RAW)
  // ---------- phase 6: MLP2 -> RA (own rows; no barrier needed) ----------
  {
    f4v acc[4] = {};
    #pragma unroll
    for (int kk=0;kk<4;kk++){
      const int reg = (kk<2) ? RB : RD;
      s8v ha = *(const s8v*)(lds + wb + reg + row_a*128 + ((64*(kk&1)+16*g) ^ swa));
      #pragma unroll
      for (int tn=0;tn<4;tn++){
        s8v wf = *(const s8v*)(w2_bf + (16*tn+c)*128 + 32*kk + 8*g);
        acc[tn] = __builtin_amdgcn_mfma_f32_16x16x32_bf16(wf, ha, acc[tn], 0,0,0);
      }
    }
    #pragma unroll
    for (int tn=0;tn<4;tn++){
      float4 b4 = *(const float4*)(b2 + 16*tn + 4*g);
      st8(lds + wb + RA + row_a*128 + ((2*(16*tn+4*g)) ^ swa),
          cvtpk(acc[tn][0]+b4.x, acc[tn][1]+b4.y), cvtpk(acc[tn][2]+b4.z, acc[tn][3]+b4.w));
    }
  }
  __syncthreads();   // b8 (-> thread map)

  // ---------- epilogue: + residual (row2 regs), coalesced store ----------
  {
    int sw = SWZ(tok);
    uint4 A0 = *(const uint4*)(lds + wtb + RA + tok*128 + ((32*cb   ) ^ sw));
    uint4 A1 = *(const uint4*)(lds + wtb + RA + tok*128 + ((32*cb+16) ^ sw));
    unsigned int pr8[8] = {A0.x,A0.y,A0.z,A0.w,A1.x,A1.y,A1.z,A1.w};
    float* op = out + ((size_t)b*64 + 16*cb)*HWs + pix;
    #pragma unroll
    for (int j=0;j<8;j++){
      op[(size_t)(2*j  )*HWs] = lo16(pr8[j]) + row2[2*j];
      op[(size_t)(2*j+1)*HWs] = hi16(pr8[j]) + row2[2*j+1];
    }
  }
}

extern "C" void kernel_launch(void* const* d_in, const int* in_sizes, int n_in,
                              void* d_out, int out_size, void* d_ws, size_t ws_size,
                              hipStream_t stream) {
  const float* x    = (const float*)d_in[0];
  const float* n1g  = (const float*)d_in[1];
  const float* n1b  = (const float*)d_in[2];
  const float* inw  = (const float*)d_in[3];
  const float* inb  = (const float*)d_in[4];
  const float* outw = (const float*)d_in[5];
  const float* outb = (const float*)d_in[6];
  const float* pw   = (const float*)d_in[7];
  const float* pb   = (const float*)d_in[8];
  const float* n2g  = (const float*)d_in[9];
  const float* n2b  = (const float*)d_in[10];
  const float* w1   = (const float*)d_in[11];
  const float* b1   = (const float*)d_in[12];
  const float* w2   = (const float*)d_in[13];
  const float* b2   = (const float*)d_in[14];

  unsigned short* wsu = (unsigned short*)d_ws;
  unsigned short* wf_bf = wsu + 28672;
  float* bfv = (float*)((char*)d_ws + 65536);

  hipLaunchKernelGGL(conv_wb, dim3(112), dim3(256), 0, stream, inw, w1, w2, wsu);
  hipLaunchKernelGGL(fuse_proj_kernel, dim3(16), dim3(256), 0, stream, outw, outb, pw, pb, wf_bf, bfv);
  hipLaunchKernelGGL(hat_main, dim3(8192), dim3(512), 0, stream,
                     x, n1g, n1b, inb, wsu, bfv, n2g, n2b, b1, b2, (float*)d_out);
}